// Round 2
// baseline (188.420 us; speedup 1.0000x reference)
//
#include <hip/hip_runtime.h>
#include <math.h>

#define PI_F 3.14159265358979323846f

// ---- 512-point complex Stockham radix-2 FFT in LDS.
// Input packed in (Ar,Ai); after 9 stages result lands in (Br,Bi), natural order.
// Enters and exits with __syncthreads().
__device__ __forceinline__ void fft512(float* Ar, float* Ai, float* Br, float* Bi, int t) {
  float* xr = Ar; float* xi = Ai; float* yr = Br; float* yi = Bi;
#pragma unroll
  for (int s = 0; s < 9; ++s) {
    __syncthreads();
    const int m = 1 << s;
    const int l = 256 >> s;
    const int j = t >> s;
    float ar = xr[t],       ai = xi[t];
    float br = xr[t + 256], bi = xi[t + 256];
    float ang = PI_F * (float)j / (float)l;   // twiddle e^{-i*pi*j/l}
    float sn, cs; __sincosf(ang, &sn, &cs);
    int o = t + (t & ~(m - 1));               // = k + 2*j*m
    float sr = ar - br, si = ai - bi;
    yr[o] = ar + br;            yi[o] = ai + bi;
    yr[o + m] = sr * cs + si * sn;
    yi[o + m] = si * cs - sr * sn;
    float* tp;
    tp = xr; xr = yr; yr = tp;
    tp = xi; xi = yi; yi = tp;
  }
  __syncthreads();
}

// Real part of X[k] of the length-1024 real-input FFT whose packed 512-pt FFT is (Br,Bi).
__device__ __forceinline__ float unpack_re(const float* Br, const float* Bi, int k) {
  int kk = k & 511, kr = (512 - k) & 511;
  float zr = Br[kk], zi = Bi[kk];
  float ur = Br[kr], ui = Bi[kr];
  float Er = 0.5f * (zr + ur);
  float Or = 0.5f * (zi + ui), Oi = 0.5f * (ur - zr);
  float th = (PI_F / 512.0f) * (float)k;
  float sn, cs; __sincosf(th, &sn, &cs);
  return Er + cs * Or + sn * Oi;
}

__device__ __forceinline__ float unpack_pwr(const float* Br, const float* Bi, int k) {
  int kk = k & 511, kr = (512 - k) & 511;
  float zr = Br[kk], zi = Bi[kk];
  float ur = Br[kr], ui = Bi[kr];
  float Er = 0.5f * (zr + ur), Ei = 0.5f * (zi - ui);
  float Or = 0.5f * (zi + ui), Oi = 0.5f * (ur - zr);
  float th = (PI_F / 512.0f) * (float)k;
  float sn, cs; __sincosf(th, &sn, &cs);
  float re = Er + cs * Or + sn * Oi;
  float im = Ei + cs * Oi - sn * Or;
  return re * re + im * im;
}

__global__ __launch_bounds__(256)
void cheaptrick_kernel(const float* __restrict__ x, const float* __restrict__ f0g,
                       float* __restrict__ out, int Tlen, int Nfr) {
  __shared__ float Ar[512], Ai[512], Br[512], Bi[512];
  __shared__ float ps[513];   // power spectrum -> log spectrum -> lifted cepstrum
  __shared__ float C[642];    // prepended-zero cumsum
  __shared__ float red[16];

  const int t = threadIdx.x;
  const int blk = blockIdx.x;
  const int b = blk / Nfr;
  const int n = blk - b * Nfr;
  const int lane = t & 63, wave = t >> 6;
  const float RATE = 15.625f;

  float f0v = f0g[blk];
  const float F_MIN = 3.0f * 16000.0f / 1021.0f;
  if (f0v <= F_MIN) f0v = 500.0f;

  // ---- windowed waveform: thread t owns samples {2t, 2t+1, 2t+512, 2t+513}
  float half_len = rintf(24000.0f / f0v);   // round-half-even matches jnp.round
  float wv[4], wd[4];
  float sw = 0.f, swin = 0.f;
  const int center = n * 80;
  const int ids[4] = {2 * t, 2 * t + 1, 2 * t + 512, 2 * t + 513};
#pragma unroll
  for (int q = 0; q < 4; ++q) {
    int base = ids[q] - 512;
    float fb = (float)base;
    float msk = (fabsf(fb) <= half_len) ? 1.0f : 0.0f;
    float win = (0.5f * cosf(PI_F * (fb / 24000.0f) * f0v) + 0.5f) * msk;
    int src = center + base;
    src = min(max(src, 0), Tlen - 1);
    float wval = x[(size_t)b * (size_t)Tlen + src] * win;
    wd[q] = win; wv[q] = wval;
    sw += wval; swin += win;
  }
#pragma unroll
  for (int off = 32; off > 0; off >>= 1) {
    sw += __shfl_down(sw, off);
    swin += __shfl_down(swin, off);
  }
  if (lane == 0) { red[wave] = sw; red[4 + wave] = swin; }
  __syncthreads();
  float mf = (red[0] + red[1] + red[2] + red[3]) / (red[4] + red[5] + red[6] + red[7]);

  // pack z[m] = w[2m] + i*w[2m+1] into (Ar,Ai)
  Ar[t]       = wv[0] - wd[0] * mf;
  Ai[t]       = wv[1] - wd[1] * mf;
  Ar[t + 256] = wv[2] - wd[2] * mf;
  Ai[t + 256] = wv[3] - wd[3] * mf;

  fft512(Ar, Ai, Br, Bi, t);

  // ---- power spectrum |rfft|^2, k in [0,513)
  {
    float p0 = unpack_pwr(Br, Bi, t);
    float p1 = unpack_pwr(Br, Bi, t + 256);
    float p2 = (t == 0) ? unpack_pwr(Br, Bi, 512) : 0.f;
    ps[t] = p0; ps[t + 256] = p1;
    if (t == 0) ps[512] = p2;
  }
  __syncthreads();

  // ---- DC correction (only k < f0/RATE <= 32 matter)
  {
    float rep = 0.f;
    bool act = (t < 40);
    float kf = (float)t;
    if (act) {
      float pos = f0v / RATE - kf;
      int lo = (int)floorf(pos);
      lo = min(max(lo, 0), 511);
      float fr = pos - (float)lo;
      rep = ps[lo] * (1.0f - fr) + ps[lo + 1] * fr;
    }
    __syncthreads();
    if (act && kf * RATE < f0v) ps[t] += rep;
  }
  __syncthreads();

  // ---- linear smoothing: cumsum of mirrored extension (641 vals), then interp
  {
    const int ebase = 3 * t;
    float e0 = 0.f, e1 = 0.f, e2 = 0.f;
    {
      int e = ebase;
      if (e < 641)     { int j = e - 64;     j = j < 0 ? -j : j; if (j > 512) j = 1024 - j; e0 = ps[j]; }
      if (e + 1 < 641) { int j = e + 1 - 64; j = j < 0 ? -j : j; if (j > 512) j = 1024 - j; e1 = ps[j]; }
      if (e + 2 < 641) { int j = e + 2 - 64; j = j < 0 ? -j : j; if (j > 512) j = 1024 - j; e2 = ps[j]; }
    }
    float psum = e0 + e1 + e2;
    float sc = psum;
#pragma unroll
    for (int off = 1; off < 64; off <<= 1) {
      float v = __shfl_up(sc, off);
      if (lane >= off) sc += v;
    }
    if (lane == 63) red[8 + wave] = sc;
    __syncthreads();
    float woff = 0.f;
#pragma unroll
    for (int w2 = 0; w2 < 4; ++w2) woff += (w2 < wave) ? red[8 + w2] : 0.f;
    float run = woff + (sc - psum);    // exclusive prefix for this chunk
    if (t == 0) C[0] = 0.f;
    if (ebase < 641)     { run += e0; C[ebase + 1] = RATE * run; }
    if (ebase + 1 < 641) { run += e1; C[ebase + 2] = RATE * run; }
    if (ebase + 2 < 641) { run += e2; C[ebase + 3] = RATE * run; }
  }
  __syncthreads();

  // ---- interp smoothed spectrum, take log  (overwrite ps with lp)
  {
    const float width = f0v * (2.0f / 3.0f);
    const float hwb = width / (2.0f * RATE);
    float s0, s1, s2 = 1.f;
#pragma unroll
    for (int r = 0; r < 3; ++r) {
      int k = (r == 0) ? t : (r == 1) ? (t + 256) : 512;
      if (r == 2 && t != 0) break;
      float kf = (float)k;
      float qh = kf + hwb + 64.5f, ql = kf - hwb + 64.5f;
      int lh = (int)floorf(qh); lh = min(max(lh, 0), 640);
      int ll = (int)floorf(ql); ll = min(max(ll, 0), 640);
      float fh = qh - (float)lh, fl = ql - (float)ll;
      float vh = C[lh] * (1.f - fh) + C[lh + 1] * fh;
      float vl = C[ll] * (1.f - fl) + C[ll + 1] * fl;
      float v = (vh - vl) / width;
      if (r == 0) s0 = v; else if (r == 1) s1 = v; else s2 = v;
    }
    ps[t] = logf(s0);
    ps[t + 256] = logf(s1);
    if (t == 0) ps[512] = logf(s2);
  }
  __syncthreads();

  // ---- cepstrum = irfft(lp): FFT of even extension, real part / 1024
  Ar[t]       = ps[2 * t];
  Ai[t]       = ps[2 * t + 1];
  Ar[t + 256] = ps[(2 * t + 512) <= 512 ? (2 * t + 512) : (1024 - (2 * t + 512))];
  Ai[t + 256] = ps[1024 - (2 * t + 513)];
  fft512(Ar, Ai, Br, Bi, t);

  // ---- lifter, write lifted cepstrum into ps
  {
    const float inv = 1.0f / 1024.0f;
    float l0, l1, l2 = 0.f;
#pragma unroll
    for (int r = 0; r < 3; ++r) {
      int k = (r == 0) ? t : (r == 1) ? (t + 256) : 512;
      if (r == 2 && t != 0) break;
      float cep = unpack_re(Br, Bi, k) * inv;
      float z = f0v * ((float)k / 16000.0f);
      float pz = PI_F * z;
      float sl = (k == 0) ? 1.0f : (sinf(pz) / pz);
      float cl = 1.3f - 0.3f * cosf(2.0f * PI_F * z);
      float v = cep * sl * cl;
      if (r == 0) l0 = v; else if (r == 1) l1 = v; else l2 = v;
    }
    ps[t] = l0; ps[t + 256] = l1;
    if (t == 0) ps[512] = l2;
  }
  __syncthreads();

  // ---- final hfft = 1024 * irfft(lifted): FFT of even extension, real part
  Ar[t]       = ps[2 * t];
  Ai[t]       = ps[2 * t + 1];
  Ar[t + 256] = ps[(2 * t + 512) <= 512 ? (2 * t + 512) : (1024 - (2 * t + 512))];
  Ai[t + 256] = ps[1024 - (2 * t + 513)];
  fft512(Ar, Ai, Br, Bi, t);

  {
    size_t ob = (size_t)blk * 513;
    out[ob + t]       = unpack_re(Br, Bi, t);
    out[ob + t + 256] = unpack_re(Br, Bi, t + 256);
    if (t == 0) out[ob + 512] = unpack_re(Br, Bi, 512);
  }
}

extern "C" void kernel_launch(void* const* d_in, const int* in_sizes, int n_in,
                              void* d_out, int out_size, void* d_ws, size_t ws_size,
                              hipStream_t stream) {
  (void)n_in; (void)d_ws; (void)ws_size; (void)out_size;
  const float* x  = (const float*)d_in[0];
  const float* f0 = (const float*)d_in[1];
  float* out = (float*)d_out;
  // in_sizes[0] = B*T, in_sizes[1] = B*N with N = T/80 + 1  =>  B = in_sizes[1] - in_sizes[0]/80
  int B = in_sizes[1] - in_sizes[0] / 80;
  if (B < 1) B = 1;
  int Tlen = in_sizes[0] / B;
  int Nfr  = in_sizes[1] / B;
  dim3 grid(in_sizes[1]), block(256);
  hipLaunchKernelGGL(cheaptrick_kernel, grid, block, 0, stream, x, f0, out, Tlen, Nfr);
}

// Round 4
// 176.248 us; speedup vs baseline: 1.0691x; 1.0691x over previous
//
#include <hip/hip_runtime.h>
#include <math.h>

#define PI_F 3.14159265358979323846f

// ---- 512-point complex Stockham radix-2 FFT in LDS, twiddles from TW table.
// TW[m] = (cos, sin)(pi*m/256). Enters and exits with __syncthreads().
__device__ __forceinline__ void fft512(float* Ar, float* Ai, float* Br, float* Bi,
                                       const float2* TW, int t) {
  float* xr = Ar; float* xi = Ai; float* yr = Br; float* yi = Bi;
#pragma unroll
  for (int s = 0; s < 9; ++s) {
    __syncthreads();
    const int m = 1 << s;
    float ar = xr[t],       ai = xi[t];
    float br = xr[t + 256], bi = xi[t + 256];
    float2 w = TW[t & ~(m - 1)];              // e^{-i*pi*(t&~(m-1))/256}
    int o = t + (t & ~(m - 1));               // = k + 2*j*m
    float sr = ar - br, si = ai - bi;
    yr[o] = ar + br;            yi[o] = ai + bi;
    yr[o + m] = sr * w.x + si * w.y;
    yi[o + m] = si * w.x - sr * w.y;
    float* tp;
    tp = xr; xr = yr; yr = tp;
    tp = xi; xi = yi; yi = tp;
  }
  __syncthreads();
}

// Real part of X[k] of the length-1024 real-input FFT whose packed 512-pt FFT is (Br,Bi).
// UP[k] = (cos, sin)(pi*k/512), valid k in [0,512].
__device__ __forceinline__ float unpack_re(const float* Br, const float* Bi,
                                           const float2* UP, int k) {
  int kk = k & 511, kr = (512 - k) & 511;
  float zr = Br[kk], zi = Bi[kk];
  float ur = Br[kr], ui = Bi[kr];
  float Er = 0.5f * (zr + ur);
  float Or = 0.5f * (zi + ui), Oi = 0.5f * (ur - zr);
  float2 w = UP[k];
  return Er + w.x * Or + w.y * Oi;
}

__device__ __forceinline__ float unpack_pwr(const float* Br, const float* Bi,
                                            const float2* UP, int k) {
  int kk = k & 511, kr = (512 - k) & 511;
  float zr = Br[kk], zi = Bi[kk];
  float ur = Br[kr], ui = Bi[kr];
  float Er = 0.5f * (zr + ur), Ei = 0.5f * (zi - ui);
  float Or = 0.5f * (zi + ui), Oi = 0.5f * (ur - zr);
  float2 w = UP[k];
  float re = Er + w.x * Or + w.y * Oi;
  float im = Ei + w.x * Oi - w.y * Or;
  return re * re + im * im;
}

__global__ __launch_bounds__(256)
void cheaptrick_kernel(const float* __restrict__ x, const float* __restrict__ f0g,
                       float* __restrict__ out, int Tlen, int Nfr) {
  __shared__ float Ar[512], Ai[512], Br[512], Bi[512];
  __shared__ float ps[513];   // power spectrum -> log spectrum -> lifted cepstrum
  __shared__ float C[642];    // prepended-zero cumsum
  __shared__ float red[16];
  __shared__ float2 TW[256];  // e^{-i pi m/256}  (FFT twiddles, all stages)
  __shared__ float2 UP[513];  // e^{-i pi k/512}  (real-FFT unpack twiddles)

  const int t = threadIdx.x;
  const int blk = blockIdx.x;
  const int b = blk / Nfr;
  const int n = blk - b * Nfr;
  const int lane = t & 63, wave = t >> 6;
  const float RATE = 15.625f;

  // ---- build twiddle tables (precise, once per block)
  {
    float sn, cs;
    sincosf((PI_F / 256.0f) * (float)t, &sn, &cs);
    TW[t] = make_float2(cs, sn);
    sincosf((PI_F / 512.0f) * (float)t, &sn, &cs);
    UP[t] = make_float2(cs, sn);
    sincosf((PI_F / 512.0f) * (float)(t + 257), &sn, &cs);
    UP[t + 257] = make_float2(cs, sn);
    if (t == 0) UP[256] = make_float2(0.0f, 1.0f);  // cos/sin(pi/2)
  }

  float f0v = f0g[blk];
  const float F_MIN = 3.0f * 16000.0f / 1021.0f;
  if (f0v <= F_MIN) f0v = 500.0f;

  // ---- windowed waveform: thread t owns samples {2t, 2t+1, 2t+512, 2t+513}
  float half_len = rintf(24000.0f / f0v);   // round-half-even matches jnp.round
  float wv[4], wd[4];
  float sw = 0.f, swin = 0.f;
  const int center = n * 80;
  const int ids[4] = {2 * t, 2 * t + 1, 2 * t + 512, 2 * t + 513};
#pragma unroll
  for (int q = 0; q < 4; ++q) {
    int base = ids[q] - 512;
    float fb = (float)base;
    float msk = (fabsf(fb) <= half_len) ? 1.0f : 0.0f;
    float win = (0.5f * __cosf(PI_F * (fb / 24000.0f) * f0v) + 0.5f) * msk;
    int src = center + base;
    src = min(max(src, 0), Tlen - 1);
    float wval = x[(size_t)b * (size_t)Tlen + src] * win;
    wd[q] = win; wv[q] = wval;
    sw += wval; swin += win;
  }
#pragma unroll
  for (int off = 32; off > 0; off >>= 1) {
    sw += __shfl_down(sw, off);
    swin += __shfl_down(swin, off);
  }
  if (lane == 0) { red[wave] = sw; red[4 + wave] = swin; }
  __syncthreads();
  float mf = (red[0] + red[1] + red[2] + red[3]) / (red[4] + red[5] + red[6] + red[7]);

  // pack z[m] = w[2m] + i*w[2m+1] into (Ar,Ai)
  Ar[t]       = wv[0] - wd[0] * mf;
  Ai[t]       = wv[1] - wd[1] * mf;
  Ar[t + 256] = wv[2] - wd[2] * mf;
  Ai[t + 256] = wv[3] - wd[3] * mf;

  fft512(Ar, Ai, Br, Bi, TW, t);

  // ---- power spectrum |rfft|^2, k in [0,513)
  {
    float p0 = unpack_pwr(Br, Bi, UP, t);
    float p1 = unpack_pwr(Br, Bi, UP, t + 256);
    float p2 = (t == 0) ? unpack_pwr(Br, Bi, UP, 512) : 0.f;
    ps[t] = p0; ps[t + 256] = p1;
    if (t == 0) ps[512] = p2;
  }
  __syncthreads();

  // ---- DC correction (only k < f0/RATE <= 32 matter)
  {
    float rep = 0.f;
    bool act = (t < 40);
    float kf = (float)t;
    if (act) {
      float pos = f0v / RATE - kf;
      int lo = (int)floorf(pos);
      lo = min(max(lo, 0), 511);
      float fr = pos - (float)lo;
      rep = ps[lo] * (1.0f - fr) + ps[lo + 1] * fr;
    }
    __syncthreads();
    if (act && kf * RATE < f0v) ps[t] += rep;
  }
  __syncthreads();

  // ---- linear smoothing: cumsum of mirrored extension (641 vals), then interp
  {
    const int ebase = 3 * t;
    float e0 = 0.f, e1 = 0.f, e2 = 0.f;
    {
      int e = ebase;
      if (e < 641)     { int j = e - 64;     j = j < 0 ? -j : j; if (j > 512) j = 1024 - j; e0 = ps[j]; }
      if (e + 1 < 641) { int j = e + 1 - 64; j = j < 0 ? -j : j; if (j > 512) j = 1024 - j; e1 = ps[j]; }
      if (e + 2 < 641) { int j = e + 2 - 64; j = j < 0 ? -j : j; if (j > 512) j = 1024 - j; e2 = ps[j]; }
    }
    float psum = e0 + e1 + e2;
    float sc = psum;
#pragma unroll
    for (int off = 1; off < 64; off <<= 1) {
      float v = __shfl_up(sc, off);
      if (lane >= off) sc += v;
    }
    if (lane == 63) red[8 + wave] = sc;
    __syncthreads();
    float woff = 0.f;
#pragma unroll
    for (int w2 = 0; w2 < 4; ++w2) woff += (w2 < wave) ? red[8 + w2] : 0.f;
    float run = woff + (sc - psum);    // exclusive prefix for this chunk
    if (t == 0) C[0] = 0.f;
    if (ebase < 641)     { run += e0; C[ebase + 1] = RATE * run; }
    if (ebase + 1 < 641) { run += e1; C[ebase + 2] = RATE * run; }
    if (ebase + 2 < 641) { run += e2; C[ebase + 3] = RATE * run; }
  }
  __syncthreads();

  // ---- interp smoothed spectrum, take log  (overwrite ps with lp)
  {
    const float width = f0v * (2.0f / 3.0f);
    const float hwb = width * (1.0f / (2.0f * RATE));
    const float winv = 1.0f / width;
    float s0, s1, s2 = 1.f;
#pragma unroll
    for (int r = 0; r < 3; ++r) {
      int k = (r == 0) ? t : (r == 1) ? (t + 256) : 512;
      if (r == 2 && t != 0) break;
      float kf = (float)k;
      float qh = kf + hwb + 64.5f, ql = kf - hwb + 64.5f;
      int lh = (int)floorf(qh); lh = min(max(lh, 0), 640);
      int ll = (int)floorf(ql); ll = min(max(ll, 0), 640);
      float fh = qh - (float)lh, fl = ql - (float)ll;
      float vh = C[lh] * (1.f - fh) + C[lh + 1] * fh;
      float vl = C[ll] * (1.f - fl) + C[ll + 1] * fl;
      float v = (vh - vl) * winv;
      if (r == 0) s0 = v; else if (r == 1) s1 = v; else s2 = v;
    }
    ps[t] = __logf(s0);
    ps[t + 256] = __logf(s1);
    if (t == 0) ps[512] = __logf(s2);
  }
  __syncthreads();

  // ---- cepstrum = irfft(lp): FFT of even extension, real part / 1024
  Ar[t]       = ps[2 * t];
  Ai[t]       = ps[2 * t + 1];
  Ar[t + 256] = ps[(2 * t + 512) <= 512 ? (2 * t + 512) : (1024 - (2 * t + 512))];
  Ai[t + 256] = ps[1024 - (2 * t + 513)];
  fft512(Ar, Ai, Br, Bi, TW, t);

  // ---- lifter, write lifted cepstrum into ps
  {
    const float inv = 1.0f / 1024.0f;
    float l0, l1, l2 = 0.f;
#pragma unroll
    for (int r = 0; r < 3; ++r) {
      int k = (r == 0) ? t : (r == 1) ? (t + 256) : 512;
      if (r == 2 && t != 0) break;
      float cep = unpack_re(Br, Bi, UP, k) * inv;
      float z = f0v * ((float)k * (1.0f / 16000.0f));
      float pz = PI_F * z;
      float s = __sinf(pz);
      float sl = (k == 0) ? 1.0f : (s / pz);
      float cl = 1.0f + 0.6f * s * s;   // 1.3 - 0.3*cos(2pi z), cos(2a)=1-2sin^2(a)
      float v = cep * sl * cl;
      if (r == 0) l0 = v; else if (r == 1) l1 = v; else l2 = v;
    }
    ps[t] = l0; ps[t + 256] = l1;
    if (t == 0) ps[512] = l2;
  }
  __syncthreads();

  // ---- final hfft = 1024 * irfft(lifted): FFT of even extension, real part
  Ar[t]       = ps[2 * t];
  Ai[t]       = ps[2 * t + 1];
  Ar[t + 256] = ps[(2 * t + 512) <= 512 ? (2 * t + 512) : (1024 - (2 * t + 512))];
  Ai[t + 256] = ps[1024 - (2 * t + 513)];
  fft512(Ar, Ai, Br, Bi, TW, t);

  {
    size_t ob = (size_t)blk * 513;
    out[ob + t]       = unpack_re(Br, Bi, UP, t);
    out[ob + t + 256] = unpack_re(Br, Bi, UP, t + 256);
    if (t == 0) out[ob + 512] = unpack_re(Br, Bi, UP, 512);
  }
}

extern "C" void kernel_launch(void* const* d_in, const int* in_sizes, int n_in,
                              void* d_out, int out_size, void* d_ws, size_t ws_size,
                              hipStream_t stream) {
  (void)n_in; (void)d_ws; (void)ws_size; (void)out_size;
  const float* x  = (const float*)d_in[0];
  const float* f0 = (const float*)d_in[1];
  float* out = (float*)d_out;
  // in_sizes[0] = B*T, in_sizes[1] = B*N with N = T/80 + 1  =>  B = in_sizes[1] - in_sizes[0]/80
  int B = in_sizes[1] - in_sizes[0] / 80;
  if (B < 1) B = 1;
  int Tlen = in_sizes[0] / B;
  int Nfr  = in_sizes[1] / B;
  dim3 grid(in_sizes[1]), block(256);
  hipLaunchKernelGGL(cheaptrick_kernel, grid, block, 0, stream, x, f0, out, Tlen, Nfr);
}